// Round 2
// baseline (429.484 us; speedup 1.0000x reference)
//
#include <hip/hip_runtime.h>
#include <stdint.h>

// out = x * mask, x: (16384, 4096) fp32.
// mask = jax.random.bernoulli(key(42), 0.9) * (1/0.9), cols < 64 forced to 0.
//
// Modern JAX (>=0.4.30) defaults to jax_threefry_partitionable=True:
//   counts1, counts2 = iota_2x32_shape(shape)   -> (hi32(f), lo32(f)) of flat idx f
//   bits1, bits2 = threefry2x32(key=(0,42), counter=(counts1, counts2))
//   bits = bits1 ^ bits2                        (32-bit output path)
//   u = bitcast((bits>>9)|0x3f800000, f32) - 1 ; keep = u < 0.9f
//   integer-exact: keep  <=>  (bits>>9) < 7549747   (0.9f == 7549747/2^23 exactly)
// For f < 2^26: hi32(f) == 0, so counter = (0, f).

#define TF_ROUND(x0, x1, d) { x0 += x1; x1 = ((x1 << (d)) | (x1 >> (32 - (d)))); x1 ^= x0; }

__device__ __forceinline__ uint32_t threefry_xor_key_0_42(uint32_t c0, uint32_t c1) {
    const uint32_t k0 = 0u;                       // key[0]
    const uint32_t k1 = 42u;                      // key[1]
    const uint32_t k2 = 0x1BD11BDAu ^ k0 ^ k1;    // parity word

    uint32_t x0 = c0 + k0;
    uint32_t x1 = c1 + k1;

    TF_ROUND(x0, x1, 13) TF_ROUND(x0, x1, 15) TF_ROUND(x0, x1, 26) TF_ROUND(x0, x1, 6)
    x0 += k1; x1 += k2 + 1u;
    TF_ROUND(x0, x1, 17) TF_ROUND(x0, x1, 29) TF_ROUND(x0, x1, 16) TF_ROUND(x0, x1, 24)
    x0 += k2; x1 += k0 + 2u;
    TF_ROUND(x0, x1, 13) TF_ROUND(x0, x1, 15) TF_ROUND(x0, x1, 26) TF_ROUND(x0, x1, 6)
    x0 += k0; x1 += k1 + 3u;
    TF_ROUND(x0, x1, 17) TF_ROUND(x0, x1, 29) TF_ROUND(x0, x1, 16) TF_ROUND(x0, x1, 24)
    x0 += k1; x1 += k2 + 4u;
    TF_ROUND(x0, x1, 13) TF_ROUND(x0, x1, 15) TF_ROUND(x0, x1, 26) TF_ROUND(x0, x1, 6)
    x0 += k2; x1 += k0 + 5u;

    return x0 ^ x1;   // partitionable 32-bit output: word0 ^ word1
}

__global__ __launch_bounds__(256) void mydropout_attack_kernel(
        const float* __restrict__ x, float* __restrict__ out, unsigned int n) {
    // Each thread: 8 consecutive elements [base, base+8). n % (8*256) == 0 here.
    unsigned int base = (blockIdx.x * 256u + threadIdx.x) * 8u;
    if (base >= n) return;

    const float SCALE = (float)(1.0 / 0.9);   // matches jnp.asarray(1.0/(1.0-0.1), f32)
    const uint32_t THRESH = 7549747u;         // 0.9f * 2^23 (exact)
    const unsigned int NCOLS = 4096u;
    const unsigned int KCOLS = 64u;

    float4 a = *reinterpret_cast<const float4*>(x + base);
    float4 b = *reinterpret_cast<const float4*>(x + base + 4);

    float m[8];
#pragma unroll
    for (int k = 0; k < 8; ++k) {
        uint32_t bits = threefry_xor_key_0_42(0u, base + (uint32_t)k);
        m[k] = ((bits >> 9) < THRESH) ? SCALE : 0.0f;
    }

    // Column kill: base % 8 == 0 and 64 % 8 == 0, so all 8 elements share the
    // (col < 64) predicate.
    if ((base & (NCOLS - 1u)) < KCOLS) {
#pragma unroll
        for (int k = 0; k < 8; ++k) m[k] = 0.0f;
    }

    float4 oa, ob;
    oa.x = a.x * m[0]; oa.y = a.y * m[1]; oa.z = a.z * m[2]; oa.w = a.w * m[3];
    ob.x = b.x * m[4]; ob.y = b.y * m[5]; ob.z = b.z * m[6]; ob.w = b.w * m[7];

    *reinterpret_cast<float4*>(out + base) = oa;
    *reinterpret_cast<float4*>(out + base + 4) = ob;
}

extern "C" void kernel_launch(void* const* d_in, const int* in_sizes, int n_in,
                              void* d_out, int out_size, void* d_ws, size_t ws_size,
                              hipStream_t stream) {
    const float* x = (const float*)d_in[0];
    float* out = (float*)d_out;

    unsigned int n = (unsigned int)out_size;        // 16384*4096 = 2^26
    unsigned int work = n / 8u;                     // one thread per 8 elements
    unsigned int threads = 256u;
    unsigned int blocks = (work + threads - 1u) / threads;

    mydropout_attack_kernel<<<dim3(blocks), dim3(threads), 0, stream>>>(x, out, n);
}